// Round 8
// baseline (258.268 us; speedup 1.0000x reference)
//
#include <hip/hip_runtime.h>
#include <math.h>

#define EPSF 1e-6f
#define MAX_ACOSH_ARGF 1e6f
#define MAX_DISTF 50.0f
#define TINYF 1e-15f

typedef float f4v __attribute__((ext_vector_type(4)));
typedef float f2v __attribute__((ext_vector_type(2)));

// ws float offsets (U region reused by OP+ZT after lift consumes it)
constexpr int OFF_U  = 0;              // 4 x 1024 x 768   = 3,145,728
constexpr int OFF_OP = 0;              // 2 x 1024 x 512   = 1,048,576 (aliases dead U)
constexpr int OFF_ZT = 1048576;        // 1024 x 264       =   270,336
constexpr int OFF_Q  = 3145728;        // 16x512x36        =   294,912
constexpr int OFF_KT = 3440640;        // 16x9x512x4       =   294,912
constexpr int OFF_VT = 3735552;        // 16x9x512x4       =   294,912

__device__ __forceinline__ float facosh(float a) {
    // a >= 1+EPS guaranteed by clamp; (a-1)(a+1) avoids a*a-1 cancellation
    return __logf(a + sqrtf((a - 1.0f) * (a + 1.0f)));
}

// ---------------- Kernel 1: QKV partial GEMM (K-split 4, LDS-free) -----------
// 1536 blocks x 256 thr = 6144 waves (24/CU). Wave = 4 rows x 128 cols,
// k-chunk of 128. Writes U[s][bt][col] partials (no bias).
__global__ __launch_bounds__(256, 4) void qkv_gemm(
    const float* __restrict__ x,
    const float* __restrict__ Wq, const float* __restrict__ Wk,
    const float* __restrict__ Wv, float* __restrict__ U)
{
    const int tid  = threadIdx.x;
    const int wid  = tid >> 6;
    const int lane = tid & 63;
    const int blk  = blockIdx.x;               // 64 rt x 6 ct x 4 s
    const int rt   = blk & 63;
    const int cs   = blk >> 6;                 // 0..23
    const int ct   = cs % 6;
    const int s    = cs / 6;
    const int m0   = rt * 16 + wid * 4;
    const int tsel = ct >> 1;
    const int n0t  = (ct & 1) * 128;
    const float* W = (tsel == 0) ? Wq : (tsel == 1) ? Wk : Wv;
    const int c0   = n0t + lane * 2;
    const int k0   = s * 128;
    const float* xb = x + m0 * 512 + k0;
    const float* wp = W + k0 * 256 + c0;

    float acc[4][2];
    #pragma unroll
    for (int r = 0; r < 4; ++r) { acc[r][0] = 0.0f; acc[r][1] = 0.0f; }

    f4v a[2][4][2];
    f2v b[2][8];

#define LDQ(B, KB)                                                      \
    { _Pragma("unroll") for (int r = 0; r < 4; ++r) {                   \
          a[B][r][0] = *(const f4v*)(xb + r * 512 + (KB));              \
          a[B][r][1] = *(const f4v*)(xb + r * 512 + (KB) + 4); }        \
      _Pragma("unroll") for (int j = 0; j < 8; ++j)                     \
          b[B][j] = *(const f2v*)(wp + ((KB) + j) * 256); }
#define STQ(B)                                                          \
    { _Pragma("unroll") for (int j = 0; j < 8; ++j) {                   \
        _Pragma("unroll") for (int r = 0; r < 4; ++r) {                 \
            const float av = a[B][r][j >> 2][j & 3];                    \
            acc[r][0] = fmaf(av, b[B][j][0], acc[r][0]);                \
            acc[r][1] = fmaf(av, b[B][j][1], acc[r][1]); } } }

    LDQ(0, 0) LDQ(1, 8)
    for (int kb = 0; kb < 112; kb += 16) {
        STQ(0) LDQ(0, kb + 16)
        STQ(1) LDQ(1, kb + 24)
    }
    STQ(0) STQ(1)
#undef LDQ
#undef STQ

    #pragma unroll
    for (int r = 0; r < 4; ++r)
        *(f2v*)(U + (s * 1024 + m0 + r) * 768 + tsel * 256 + c0) =
            f2v{acc[r][0], acc[r][1]};
}

// ---------------- Kernel 2: reduce partials + bias + hyperboloid lift --------
// 1024 blocks (one bt) x 768 thr (thread = one col). 32-lane group = one
// (tensor,head); Q row-major padded [bh][t][36], K/V transposed-f4 [bh][j][t][4].
__global__ __launch_bounds__(768) void lift_kernel(
    const float* __restrict__ U,
    const float* __restrict__ bq, const float* __restrict__ bk,
    const float* __restrict__ bv,
    float* __restrict__ Qp, float* __restrict__ KT, float* __restrict__ VT)
{
    const int bt = blockIdx.x;
    const int b  = bt >> 9, t = bt & 511;
    const int j  = threadIdx.x;                // 0..767
    const int tsel = j >> 8, h = (j >> 5) & 7, cin = j & 31;

    const float* bias = (tsel == 0) ? bq : (tsel == 1) ? bk : bv;
    float u = bias[j & 255];
    #pragma unroll
    for (int s = 0; s < 4; ++s) u += U[s * 786432 + bt * 768 + j];

    float n2 = u * u;
    #pragma unroll
    for (int msk = 1; msk < 32; msk <<= 1) n2 += __shfl_xor(n2, msk, 64);
    n2 = fmaxf(n2, TINYF);
    const float vn = sqrtf(n2);
    const float ch = coshf(vn);
    const float sh = sinhf(vn) / fmaxf(vn, TINYF);
    const float xx = fmaf(sh * sh, n2, -ch * ch);   // mink(y,y) ~ -1
    const float scale = sqrtf(fmaxf(fabsf(xx), TINYF));
    const float fs = sh / scale;
    const float tc = fabsf(ch / scale);
    const int bh = b * 8 + h;

    if (tsel == 0) {
        float* qp = Qp + (bh * 512 + t) * 36;
        qp[1 + cin] = fs * u;
        if (cin == 0) { qp[0] = tc; qp[33] = 0.0f; qp[34] = 0.0f; qp[35] = 0.0f; }
    } else {
        float* P = ((tsel == 1) ? KT : VT) + bh * 18432;   // [9][512][4]
        const int a0 = 1 + cin;
        P[(a0 >> 2) * 2048 + t * 4 + (a0 & 3)] = fs * u;
        if (cin == 0) {
            P[t * 4] = tc;
            P[8 * 2048 + t * 4 + 1] = 0.0f;
            P[8 * 2048 + t * 4 + 2] = 0.0f;
            P[8 * 2048 + t * 4 + 3] = 0.0f;
        }
    }
}

// ---------------- Kernel 3: attention + Karcher step + log-map ---------------
// 1024 blocks x 256 thr = 4096 waves (16/CU). Block = 8 q; wave w handles
// q-quad (w>>1) for k-half (w&1): 16-lane group per q, lane t owns k=t+16*st.
// K/V read L2-direct from transposed layout; k-halves merged via tiny LDS.
__global__ __launch_bounds__(256, 4) void attn_kernel(
    const float* __restrict__ Qp, const float* __restrict__ KT,
    const float* __restrict__ VT, float* __restrict__ ZT)
{
    __shared__ float part[2][4][34];

    const int tid   = threadIdx.x;
    const int blk   = blockIdx.x;         // 0..1023
    const int bh    = blk >> 6;
    const int q0    = (blk & 63) * 8;
    const int wid   = tid >> 6;
    const int lane  = tid & 63;
    const int g     = lane >> 4;
    const int t     = lane & 15;
    const int quad  = wid >> 1;
    const int khalf = wid & 1;
    const int qi    = q0 + quad * 4 + g;

    // q row (negated-spatial), padded to 36
    float qn[36];
    {
        const float* qp = Qp + (bh * 512 + qi) * 36;
        #pragma unroll
        for (int jj = 0; jj < 9; ++jj) {
            const f4v v = *(const f4v*)(qp + 4 * jj);
            #pragma unroll
            for (int i = 0; i < 4; ++i) {
                const int a = 4 * jj + i;
                qn[a] = (a == 0) ? v[i] : -v[i];
            }
        }
    }

    const f4v* K4 = (const f4v*)KT + bh * 4608;
    const f4v* V4 = (const f4v*)VT + bh * 4608;

    float l = 0.0f;
    float ac[33];
    #pragma unroll
    for (int a = 0; a < 33; ++a) ac[a] = 0.0f;

    for (int st = 0; st < 16; ++st) {
        const int k = t + 16 * st + 256 * khalf;
        f4v kr[9], vr[9];
        #pragma unroll
        for (int jj = 0; jj < 9; ++jj) kr[jj] = K4[jj * 512 + k];
        #pragma unroll
        for (int jj = 0; jj < 9; ++jj) vr[jj] = V4[jj * 512 + k];

        float p0 = 0.f, p1 = 0.f, p2 = 0.f, p3 = 0.f;
        #pragma unroll
        for (int jj = 0; jj < 9; ++jj) {
            p0 = fmaf(qn[4 * jj],     kr[jj][0], p0);
            p1 = fmaf(qn[4 * jj + 1], kr[jj][1], p1);
            p2 = fmaf(qn[4 * jj + 2], kr[jj][2], p2);
            p3 = fmaf(qn[4 * jj + 3], kr[jj][3], p3);
        }
        const float a1 = (p0 + p1) + (p2 + p3);

        float r0 = 0.f, r1 = 0.f, r2 = 0.f, r3 = 0.f;
        #pragma unroll
        for (int jj = 0; jj < 9; ++jj) {
            r0 = fmaf(qn[4 * jj],     vr[jj][0], r0);
            r1 = fmaf(qn[4 * jj + 1], vr[jj][1], r1);
            r2 = fmaf(qn[4 * jj + 2], vr[jj][2], r2);
            r3 = fmaf(qn[4 * jj + 3], vr[jj][3], r3);
        }
        const float a2 = (r0 + r1) + (r2 + r3);

        const float a1c = fminf(fmaxf(a1, 1.0f + EPSF), MAX_ACOSH_ARGF);
        const float dd  = fminf(facosh(a1c), MAX_DISTF);
        const float e   = __expf(-dd * dd);          // scores <= 0: no max needed
        const float a2c = fminf(fmaxf(a2, 1.0f + EPSF), MAX_ACOSH_ARGF);
        const float w   = e * facosh(a2c);
        l += e;
        #pragma unroll
        for (int a = 0; a < 33; ++a) ac[a] = fmaf(w, vr[a >> 2][a & 3], ac[a]);
    }

    // intra-group (16-lane) butterfly: all lanes get the group sums
    #pragma unroll
    for (int msk = 1; msk < 16; msk <<= 1) l += __shfl_xor(l, msk, 64);
    #pragma unroll
    for (int a = 0; a < 33; ++a) {
        float v = ac[a];
        #pragma unroll
        for (int msk = 1; msk < 16; msk <<= 1) v += __shfl_xor(v, msk, 64);
        ac[a] = v;
    }

    // cross-wave merge of the two k-halves
    if (khalf == 1 && t == 0) {
        part[quad][g][0] = l;
        #pragma unroll
        for (int a = 0; a < 33; ++a) part[quad][g][1 + a] = ac[a];
    }
    __syncthreads();
    if (khalf == 1) return;

    l += part[quad][g][0];
    #pragma unroll
    for (int a = 0; a < 33; ++a) ac[a] += part[quad][g][1 + a];

    // ---- epilogue (redundant within group; lane t==0 stores) ----
    // fold scalar Q-side: step ∝ Σw·v + (Σw·a2)·q ; Σw·a2 = <qn, ac>
    float sw = 0.0f;
    #pragma unroll
    for (int a = 0; a < 33; ++a) sw = fmaf(qn[a], ac[a], sw);
    const float un_c   = 3.1622776601683794e-8f;     // sqrt(1e-15)
    const float inv_un = (1.0f / l) / un_c;
    ac[0] = fmaf(sw, qn[0], ac[0]) * inv_un;
    #pragma unroll
    for (int a = 1; a < 33; ++a) ac[a] = fmaf(-sw, qn[a], ac[a]) * inv_un;

    float mk = -ac[0] * ac[0];
    #pragma unroll
    for (int a = 1; a < 33; ++a) mk = fmaf(ac[a], ac[a], mk);
    const float snorm = sqrtf(fmaxf(mk, TINYF));
    const float fac   = fminf(snorm, 20.0f) / (snorm + 1e-9f);
    #pragma unroll
    for (int a = 0; a < 33; ++a) ac[a] *= fac;

    float mk2 = -ac[0] * ac[0];
    #pragma unroll
    for (int a = 1; a < 33; ++a) mk2 = fmaf(ac[a], ac[a], mk2);
    const float vn  = sqrtf(fmaxf(mk2, TINYF));
    const float ch  = coshf(vn);
    const float shr = sinhf(vn) / fmaxf(vn, TINYF);
    ac[0] = fmaf(ch, qn[0], shr * ac[0]);
    #pragma unroll
    for (int a = 1; a < 33; ++a) ac[a] = fmaf(-ch, qn[a], shr * ac[a]);   // y

    float xx = -ac[0] * ac[0];
    #pragma unroll
    for (int a = 1; a < 33; ++a) xx = fmaf(ac[a], ac[a], xx);
    const float scale = sqrtf(fmaxf(fabsf(xx), TINYF));

    const float Y0  = fabsf(ac[0] / scale);
    const float al3 = fminf(fmaxf(Y0, 1.0f + EPSF), MAX_ACOSH_ARGF);
    const float d3  = acoshf(al3);
    const float f3  = d3 / un_c;

    if (t == 0) {
        const int b = bh >> 3, h = bh & 7;
        float* zp = ZT + (b * 512 + qi) * 264 + h * 33;
        zp[0] = f3 * (Y0 + al3);
        const float fsc = f3 / scale;
        #pragma unroll
        for (int a = 1; a < 33; ++a) zp[a] = fsc * ac[a];
    }
}

// ---------------- Kernel 4: out partial GEMM (K-split 2, LDS-free) -----------
// 1024 blocks x 256 thr = 4096 waves (16/CU). Wave = 4 rows x 64 cols
// (lane = col), k-chunk 132. Writes OP[s][bt][col].
__global__ __launch_bounds__(256, 4) void out_gemm(
    const float* __restrict__ ZT, const float* __restrict__ Wo,
    float* __restrict__ OP)
{
    const int tid  = threadIdx.x;
    const int wid  = tid >> 6;
    const int lane = tid & 63;
    const int blk  = blockIdx.x;               // 64 rt x 8 ct x 2 s
    const int rt   = blk & 63;
    const int cs   = blk >> 6;
    const int ct   = cs & 7;
    const int s    = cs >> 3;
    const int m0   = rt * 16 + wid * 4;
    const int c0   = ct * 64 + lane;
    const int k0   = s * 132;
    const float* zb = ZT + m0 * 264 + k0;
    const float* wp = Wo + k0 * 512 + c0;

    float acc[4] = {0.f, 0.f, 0.f, 0.f};
    f4v a[2][4];
    float bv[2][4];

#define LDO(B, KK)                                                      \
    { _Pragma("unroll") for (int r = 0; r < 4; ++r)                     \
          a[B][r] = *(const f4v*)(zb + r * 264 + (KK));                 \
      _Pragma("unroll") for (int jj = 0; jj < 4; ++jj)                  \
          bv[B][jj] = wp[((KK) + jj) * 512]; }
#define STO(B)                                                          \
    { _Pragma("unroll") for (int jj = 0; jj < 4; ++jj) {                \
        _Pragma("unroll") for (int r = 0; r < 4; ++r)                   \
            acc[r] = fmaf(a[B][r][jj], bv[B][jj], acc[r]); } }

    LDO(0, 0) LDO(1, 4)
    for (int kb = 0; kb < 120; kb += 8) {     // 15 iterations
        STO(0) LDO(0, kb + 8)
        STO(1) LDO(1, kb + 12)
    }
    STO(0) LDO(0, 128)                         // groups 30,31,32
    STO(1)
    STO(0)
#undef LDO
#undef STO

    #pragma unroll
    for (int r = 0; r < 4; ++r)
        OP[s * 524288 + (m0 + r) * 512 + c0] = acc[r];
}

// ---------------- Kernel 5: out = OP0 + OP1 + bias ---------------------------
__global__ __launch_bounds__(256) void out_reduce(
    const float* __restrict__ OP, const float* __restrict__ bo,
    float* __restrict__ out)
{
    const int i4 = blockIdx.x * 256 + threadIdx.x;   // 131072 f4
    const f4v p0 = ((const f4v*)OP)[i4];
    const f4v p1 = ((const f4v*)OP)[i4 + 131072];
    const f4v bb = ((const f4v*)bo)[i4 & 127];
    ((f4v*)out)[i4] = p0 + p1 + bb;
}

extern "C" void kernel_launch(void* const* d_in, const int* in_sizes, int n_in,
                              void* d_out, int out_size, void* d_ws, size_t ws_size,
                              hipStream_t stream) {
    const float* x  = (const float*)d_in[0];
    const float* Wq = (const float*)d_in[1];
    const float* bq = (const float*)d_in[2];
    const float* Wk = (const float*)d_in[3];
    const float* bk = (const float*)d_in[4];
    const float* Wv = (const float*)d_in[5];
    const float* bv = (const float*)d_in[6];
    const float* Wo = (const float*)d_in[7];
    const float* bo = (const float*)d_in[8];
    float* out = (float*)d_out;
    float* ws  = (float*)d_ws;

    float* U   = ws + OFF_U;
    float* OP  = ws + OFF_OP;
    float* ZTp = ws + OFF_ZT;
    float* Qp  = ws + OFF_Q;
    float* KT  = ws + OFF_KT;
    float* VT  = ws + OFF_VT;

    qkv_gemm<<<1536, 256, 0, stream>>>(x, Wq, Wk, Wv, U);
    lift_kernel<<<1024, 768, 0, stream>>>(U, bq, bk, bv, Qp, KT, VT);
    attn_kernel<<<1024, 256, 0, stream>>>(Qp, KT, VT, ZTp);
    out_gemm<<<1024, 256, 0, stream>>>(ZTp, Wo, OP);
    out_reduce<<<512, 256, 0, stream>>>(OP, bo, out);
}

// Round 9
// 203.617 us; speedup vs baseline: 1.2684x; 1.2684x over previous
//
#include <hip/hip_runtime.h>
#include <math.h>

#define EPSF 1e-6f
#define MAX_ACOSH_ARGF 1e6f
#define MAX_DISTF 50.0f
#define TINYF 1e-15f

typedef float f4v __attribute__((ext_vector_type(4)));
typedef float f2v __attribute__((ext_vector_type(2)));

// ws float offsets (U region reused by OP+ZT after lift consumes it)
constexpr int OFF_U  = 0;              // 4 x 1024 x 768   = 3,145,728
constexpr int OFF_OP = 0;              // 2 x 1024 x 512   = 1,048,576 (aliases dead U)
constexpr int OFF_ZT = 1048576;        // 1024 x 264       =   270,336
constexpr int OFF_Q  = 3145728;        // 16x512x36        =   294,912
constexpr int OFF_KT = 3440640;        // 16x9x512x4       =   294,912
constexpr int OFF_VT = 3735552;        // 16x9x512x4       =   294,912

__device__ __forceinline__ float facosh(float a) {
    // a >= 1+EPS guaranteed by clamp; (a-1)(a+1) avoids a*a-1 cancellation
    return __logf(a + sqrtf((a - 1.0f) * (a + 1.0f)));
}

// ---------------- Kernel 1: QKV partial GEMM (K-split 4, LDS-free) -----------
// 1536 blocks x 256 thr = 6144 waves (24/CU). Wave = 4 rows x 128 cols,
// k-chunk of 128. Writes U[s][bt][col] partials (no bias).
__global__ __launch_bounds__(256, 4) void qkv_gemm(
    const float* __restrict__ x,
    const float* __restrict__ Wq, const float* __restrict__ Wk,
    const float* __restrict__ Wv, float* __restrict__ U)
{
    const int tid  = threadIdx.x;
    const int wid  = tid >> 6;
    const int lane = tid & 63;
    const int blk  = blockIdx.x;               // 64 rt x 6 ct x 4 s
    const int rt   = blk & 63;
    const int cs   = blk >> 6;                 // 0..23
    const int ct   = cs % 6;
    const int s    = cs / 6;
    const int m0   = rt * 16 + wid * 4;
    const int tsel = ct >> 1;
    const int n0t  = (ct & 1) * 128;
    const float* W = (tsel == 0) ? Wq : (tsel == 1) ? Wk : Wv;
    const int c0   = n0t + lane * 2;
    const int k0   = s * 128;
    const float* xb = x + m0 * 512 + k0;
    const float* wp = W + k0 * 256 + c0;

    float acc[4][2];
    #pragma unroll
    for (int r = 0; r < 4; ++r) { acc[r][0] = 0.0f; acc[r][1] = 0.0f; }

    f4v a[2][4][2];
    f2v b[2][8];

#define LDQ(B, KB)                                                      \
    { _Pragma("unroll") for (int r = 0; r < 4; ++r) {                   \
          a[B][r][0] = *(const f4v*)(xb + r * 512 + (KB));              \
          a[B][r][1] = *(const f4v*)(xb + r * 512 + (KB) + 4); }        \
      _Pragma("unroll") for (int j = 0; j < 8; ++j)                     \
          b[B][j] = *(const f2v*)(wp + ((KB) + j) * 256); }
#define STQ(B)                                                          \
    { _Pragma("unroll") for (int j = 0; j < 8; ++j) {                   \
        _Pragma("unroll") for (int r = 0; r < 4; ++r) {                 \
            const float av = a[B][r][j >> 2][j & 3];                    \
            acc[r][0] = fmaf(av, b[B][j][0], acc[r][0]);                \
            acc[r][1] = fmaf(av, b[B][j][1], acc[r][1]); } } }

    LDQ(0, 0) LDQ(1, 8)
    for (int kb = 0; kb < 112; kb += 16) {
        STQ(0) LDQ(0, kb + 16)
        STQ(1) LDQ(1, kb + 24)
    }
    STQ(0) STQ(1)
#undef LDQ
#undef STQ

    #pragma unroll
    for (int r = 0; r < 4; ++r)
        *(f2v*)(U + (s * 1024 + m0 + r) * 768 + tsel * 256 + c0) =
            f2v{acc[r][0], acc[r][1]};
}

// ---------------- Kernel 2: reduce partials + bias + hyperboloid lift --------
// 1024 blocks (one bt) x 768 thr (thread = one col). 32-lane group = one
// (tensor,head); Q row-major padded [bh][t][36], K/V transposed-f4 [bh][j][t][4].
__global__ __launch_bounds__(768) void lift_kernel(
    const float* __restrict__ U,
    const float* __restrict__ bq, const float* __restrict__ bk,
    const float* __restrict__ bv,
    float* __restrict__ Qp, float* __restrict__ KT, float* __restrict__ VT)
{
    const int bt = blockIdx.x;
    const int b  = bt >> 9, t = bt & 511;
    const int j  = threadIdx.x;                // 0..767
    const int tsel = j >> 8, h = (j >> 5) & 7, cin = j & 31;

    const float* bias = (tsel == 0) ? bq : (tsel == 1) ? bk : bv;
    float u = bias[j & 255];
    #pragma unroll
    for (int s = 0; s < 4; ++s) u += U[s * 786432 + bt * 768 + j];

    float n2 = u * u;
    #pragma unroll
    for (int msk = 1; msk < 32; msk <<= 1) n2 += __shfl_xor(n2, msk, 64);
    n2 = fmaxf(n2, TINYF);
    const float vn = sqrtf(n2);
    const float ch = coshf(vn);
    const float sh = sinhf(vn) / fmaxf(vn, TINYF);
    const float xx = fmaf(sh * sh, n2, -ch * ch);   // mink(y,y) ~ -1
    const float scale = sqrtf(fmaxf(fabsf(xx), TINYF));
    const float fs = sh / scale;
    const float tc = fabsf(ch / scale);
    const int bh = b * 8 + h;

    if (tsel == 0) {
        float* qp = Qp + (bh * 512 + t) * 36;
        qp[1 + cin] = fs * u;
        if (cin == 0) { qp[0] = tc; qp[33] = 0.0f; qp[34] = 0.0f; qp[35] = 0.0f; }
    } else {
        float* P = ((tsel == 1) ? KT : VT) + bh * 18432;   // [9][512][4]
        const int a0 = 1 + cin;
        P[(a0 >> 2) * 2048 + t * 4 + (a0 & 3)] = fs * u;
        if (cin == 0) {
            P[t * 4] = tc;
            P[8 * 2048 + t * 4 + 1] = 0.0f;
            P[8 * 2048 + t * 4 + 2] = 0.0f;
            P[8 * 2048 + t * 4 + 3] = 0.0f;
        }
    }
}

// ---------------- Kernel 3: attention + Karcher step + log-map ---------------
// 1024 blocks x 256 thr = 4096 waves. Block = 8 q; wave w handles q-quad
// (w>>1) for k-half (w&1): 16-lane group per q, lane t owns k=t+16*st.
// K/V read L2-direct from transposed layout; k-halves merged via tiny LDS.
// PLAIN launch bounds: the (256,4) min-waves hint capped VGPRs at 64 and
// spilled the ~130-reg working set (67 MB scratch writes, r8 post-mortem).
__global__ __launch_bounds__(256) void attn_kernel(
    const float* __restrict__ Qp, const float* __restrict__ KT,
    const float* __restrict__ VT, float* __restrict__ ZT)
{
    __shared__ float part[2][4][34];

    const int tid   = threadIdx.x;
    const int blk   = blockIdx.x;         // 0..1023
    const int bh    = blk >> 6;
    const int q0    = (blk & 63) * 8;
    const int wid   = tid >> 6;
    const int lane  = tid & 63;
    const int g     = lane >> 4;
    const int t     = lane & 15;
    const int quad  = wid >> 1;
    const int khalf = wid & 1;
    const int qi    = q0 + quad * 4 + g;

    // q row (negated-spatial), padded to 36
    float qn[36];
    {
        const float* qp = Qp + (bh * 512 + qi) * 36;
        #pragma unroll
        for (int jj = 0; jj < 9; ++jj) {
            const f4v v = *(const f4v*)(qp + 4 * jj);
            #pragma unroll
            for (int i = 0; i < 4; ++i) {
                const int a = 4 * jj + i;
                qn[a] = (a == 0) ? v[i] : -v[i];
            }
        }
    }

    const f4v* K4 = (const f4v*)KT + bh * 4608;
    const f4v* V4 = (const f4v*)VT + bh * 4608;

    float l = 0.0f;
    float ac[33];
    #pragma unroll
    for (int a = 0; a < 33; ++a) ac[a] = 0.0f;

    for (int st = 0; st < 16; ++st) {
        const int k = t + 16 * st + 256 * khalf;
        f4v kr[9], vr[9];
        #pragma unroll
        for (int jj = 0; jj < 9; ++jj) kr[jj] = K4[jj * 512 + k];
        #pragma unroll
        for (int jj = 0; jj < 9; ++jj) vr[jj] = V4[jj * 512 + k];

        float p0 = 0.f, p1 = 0.f, p2 = 0.f, p3 = 0.f;
        #pragma unroll
        for (int jj = 0; jj < 9; ++jj) {
            p0 = fmaf(qn[4 * jj],     kr[jj][0], p0);
            p1 = fmaf(qn[4 * jj + 1], kr[jj][1], p1);
            p2 = fmaf(qn[4 * jj + 2], kr[jj][2], p2);
            p3 = fmaf(qn[4 * jj + 3], kr[jj][3], p3);
        }
        const float a1 = (p0 + p1) + (p2 + p3);

        float r0 = 0.f, r1 = 0.f, r2 = 0.f, r3 = 0.f;
        #pragma unroll
        for (int jj = 0; jj < 9; ++jj) {
            r0 = fmaf(qn[4 * jj],     vr[jj][0], r0);
            r1 = fmaf(qn[4 * jj + 1], vr[jj][1], r1);
            r2 = fmaf(qn[4 * jj + 2], vr[jj][2], r2);
            r3 = fmaf(qn[4 * jj + 3], vr[jj][3], r3);
        }
        const float a2 = (r0 + r1) + (r2 + r3);

        const float a1c = fminf(fmaxf(a1, 1.0f + EPSF), MAX_ACOSH_ARGF);
        const float dd  = fminf(facosh(a1c), MAX_DISTF);
        const float e   = __expf(-dd * dd);          // scores <= 0: no max needed
        const float a2c = fminf(fmaxf(a2, 1.0f + EPSF), MAX_ACOSH_ARGF);
        const float w   = e * facosh(a2c);
        l += e;
        #pragma unroll
        for (int a = 0; a < 33; ++a) ac[a] = fmaf(w, vr[a >> 2][a & 3], ac[a]);
    }

    // intra-group (16-lane) butterfly: all lanes get the group sums
    #pragma unroll
    for (int msk = 1; msk < 16; msk <<= 1) l += __shfl_xor(l, msk, 64);
    #pragma unroll
    for (int a = 0; a < 33; ++a) {
        float v = ac[a];
        #pragma unroll
        for (int msk = 1; msk < 16; msk <<= 1) v += __shfl_xor(v, msk, 64);
        ac[a] = v;
    }

    // cross-wave merge of the two k-halves
    if (khalf == 1 && t == 0) {
        part[quad][g][0] = l;
        #pragma unroll
        for (int a = 0; a < 33; ++a) part[quad][g][1 + a] = ac[a];
    }
    __syncthreads();
    if (khalf == 1) return;

    l += part[quad][g][0];
    #pragma unroll
    for (int a = 0; a < 33; ++a) ac[a] += part[quad][g][1 + a];

    // ---- epilogue (redundant within group; lane t==0 stores) ----
    // fold scalar Q-side: step ∝ Σw·v + (Σw·a2)·q ; Σw·a2 = <qn, ac>
    float sw = 0.0f;
    #pragma unroll
    for (int a = 0; a < 33; ++a) sw = fmaf(qn[a], ac[a], sw);
    const float un_c   = 3.1622776601683794e-8f;     // sqrt(1e-15)
    const float inv_un = (1.0f / l) / un_c;
    ac[0] = fmaf(sw, qn[0], ac[0]) * inv_un;
    #pragma unroll
    for (int a = 1; a < 33; ++a) ac[a] = fmaf(-sw, qn[a], ac[a]) * inv_un;

    float mk = -ac[0] * ac[0];
    #pragma unroll
    for (int a = 1; a < 33; ++a) mk = fmaf(ac[a], ac[a], mk);
    const float snorm = sqrtf(fmaxf(mk, TINYF));
    const float fac   = fminf(snorm, 20.0f) / (snorm + 1e-9f);
    #pragma unroll
    for (int a = 0; a < 33; ++a) ac[a] *= fac;

    float mk2 = -ac[0] * ac[0];
    #pragma unroll
    for (int a = 1; a < 33; ++a) mk2 = fmaf(ac[a], ac[a], mk2);
    const float vn  = sqrtf(fmaxf(mk2, TINYF));
    const float ch  = coshf(vn);
    const float shr = sinhf(vn) / fmaxf(vn, TINYF);
    ac[0] = fmaf(ch, qn[0], shr * ac[0]);
    #pragma unroll
    for (int a = 1; a < 33; ++a) ac[a] = fmaf(-ch, qn[a], shr * ac[a]);   // y

    float xx = -ac[0] * ac[0];
    #pragma unroll
    for (int a = 1; a < 33; ++a) xx = fmaf(ac[a], ac[a], xx);
    const float scale = sqrtf(fmaxf(fabsf(xx), TINYF));

    const float Y0  = fabsf(ac[0] / scale);
    const float al3 = fminf(fmaxf(Y0, 1.0f + EPSF), MAX_ACOSH_ARGF);
    const float d3  = acoshf(al3);
    const float f3  = d3 / un_c;

    if (t == 0) {
        const int b = bh >> 3, h = bh & 7;
        float* zp = ZT + (b * 512 + qi) * 264 + h * 33;
        zp[0] = f3 * (Y0 + al3);
        const float fsc = f3 / scale;
        #pragma unroll
        for (int a = 1; a < 33; ++a) zp[a] = fsc * ac[a];
    }
}

// ---------------- Kernel 4: out partial GEMM (K-split 2, LDS-free) -----------
// 1024 blocks x 256 thr = 4096 waves (16/CU). Wave = 4 rows x 64 cols
// (lane = col), k-chunk 132. Writes OP[s][bt][col].
__global__ __launch_bounds__(256, 4) void out_gemm(
    const float* __restrict__ ZT, const float* __restrict__ Wo,
    float* __restrict__ OP)
{
    const int tid  = threadIdx.x;
    const int wid  = tid >> 6;
    const int lane = tid & 63;
    const int blk  = blockIdx.x;               // 64 rt x 8 ct x 2 s
    const int rt   = blk & 63;
    const int cs   = blk >> 6;
    const int ct   = cs & 7;
    const int s    = cs >> 3;
    const int m0   = rt * 16 + wid * 4;
    const int c0   = ct * 64 + lane;
    const int k0   = s * 132;
    const float* zb = ZT + m0 * 264 + k0;
    const float* wp = Wo + k0 * 512 + c0;

    float acc[4] = {0.f, 0.f, 0.f, 0.f};
    f4v a[2][4];
    float bv[2][4];

#define LDO(B, KK)                                                      \
    { _Pragma("unroll") for (int r = 0; r < 4; ++r)                     \
          a[B][r] = *(const f4v*)(zb + r * 264 + (KK));                 \
      _Pragma("unroll") for (int jj = 0; jj < 4; ++jj)                  \
          bv[B][jj] = wp[((KK) + jj) * 512]; }
#define STO(B)                                                          \
    { _Pragma("unroll") for (int jj = 0; jj < 4; ++jj) {                \
        _Pragma("unroll") for (int r = 0; r < 4; ++r)                   \
            acc[r] = fmaf(a[B][r][jj], bv[B][jj], acc[r]); } }

    LDO(0, 0) LDO(1, 4)
    for (int kb = 0; kb < 120; kb += 8) {     // 15 iterations
        STO(0) LDO(0, kb + 8)
        STO(1) LDO(1, kb + 12)
    }
    STO(0) LDO(0, 128)                         // groups 30,31,32
    STO(1)
    STO(0)
#undef LDO
#undef STO

    #pragma unroll
    for (int r = 0; r < 4; ++r)
        OP[s * 524288 + (m0 + r) * 512 + c0] = acc[r];
}

// ---------------- Kernel 5: out = OP0 + OP1 + bias ---------------------------
__global__ __launch_bounds__(256) void out_reduce(
    const float* __restrict__ OP, const float* __restrict__ bo,
    float* __restrict__ out)
{
    const int i4 = blockIdx.x * 256 + threadIdx.x;   // 131072 f4
    const f4v p0 = ((const f4v*)OP)[i4];
    const f4v p1 = ((const f4v*)OP)[i4 + 131072];
    const f4v bb = ((const f4v*)bo)[i4 & 127];
    ((f4v*)out)[i4] = p0 + p1 + bb;
}

extern "C" void kernel_launch(void* const* d_in, const int* in_sizes, int n_in,
                              void* d_out, int out_size, void* d_ws, size_t ws_size,
                              hipStream_t stream) {
    const float* x  = (const float*)d_in[0];
    const float* Wq = (const float*)d_in[1];
    const float* bq = (const float*)d_in[2];
    const float* Wk = (const float*)d_in[3];
    const float* bk = (const float*)d_in[4];
    const float* Wv = (const float*)d_in[5];
    const float* bv = (const float*)d_in[6];
    const float* Wo = (const float*)d_in[7];
    const float* bo = (const float*)d_in[8];
    float* out = (float*)d_out;
    float* ws  = (float*)d_ws;

    float* U   = ws + OFF_U;
    float* OP  = ws + OFF_OP;
    float* ZTp = ws + OFF_ZT;
    float* Qp  = ws + OFF_Q;
    float* KT  = ws + OFF_KT;
    float* VT  = ws + OFF_VT;

    qkv_gemm<<<1536, 256, 0, stream>>>(x, Wq, Wk, Wv, U);
    lift_kernel<<<1024, 768, 0, stream>>>(U, bq, bk, bv, Qp, KT, VT);
    attn_kernel<<<1024, 256, 0, stream>>>(Qp, KT, VT, ZTp);
    out_gemm<<<1024, 256, 0, stream>>>(ZTp, Wo, OP);
    out_reduce<<<512, 256, 0, stream>>>(OP, bo, out);
}